// Round 6
// baseline (326.480 us; speedup 1.0000x reference)
//
#include <hip/hip_runtime.h>
#include <hip/hip_bf16.h>
#include <stdint.h>

#define GSIZE 64
#define MDIM 4096
#define KDIM 4096
#define NDIM 4096
#define RANK 32
#define KE   4160   // K + 32 (lora) + 32 (zero pad) -> 65 * 64
#define NG   64     // K / GSIZE
#define NSPLIT 8    // split-K factor for lora-down GEMM

typedef __bf16 bf16x4 __attribute__((ext_vector_type(4)));
typedef __bf16 bf16x8 __attribute__((ext_vector_type(8)));
typedef float  f32x4  __attribute__((ext_vector_type(4)));

#define GPTR(p) ((__attribute__((address_space(1))) void*)(uintptr_t)(p))
#define LPTR(p) ((__attribute__((address_space(3))) void*)(p))

// ---------------------------------------------------------------------------
// Round-5 change: k_prep split into THREE role kernels so each role gets its
// own VGPR/LDS budget (occupancy theory: fused kernel charged LORAT's ~90
// VGPR + 10KB LDS to every block, capping the BW-bound roles at ~5 blocks/CU)
// and so each role shows up in the profile with its own counters.
// Order: LORAT (x cold) -> WPREP (qw) -> QUANT (x again, now L3-hot) -> FIN.
// ---------------------------------------------------------------------------

// ---------------- LORAT: t_partial = x @ lora_down (split-K) ----------------
__global__ __launch_bounds__(256) void k_lorat(const float* __restrict__ x,
                                               const float* __restrict__ ld,
                                               float* __restrict__ tws) {
    __shared__ __attribute__((aligned(16))) char smem[10240];
    __bf16* AsL = (__bf16*)smem;            // [128][32], xor-swizzled
    __bf16* BsL = (__bf16*)(smem + 8192);   // [32 n][32 k]
    int b   = blockIdx.x;
    int tid = threadIdx.x;
    int m0    = (b & 31) * 128;
    int sp    = b >> 5;                     // 0..7
    int kbase = sp * 512;
    int lane = tid & 63;
    int wave = tid >> 6;
    int quad = lane >> 4;
    int mrow = lane & 15;

    f32x4 z = {0.f, 0.f, 0.f, 0.f};
    f32x4 acc[2][2];
    acc[0][0] = z; acc[0][1] = z; acc[1][0] = z; acc[1][1] = z;

    for (int step = 0; step < 16; ++step) {
        int kk = kbase + step * 32;
        // A staging: fp32 load + convert; linear slots (conflict-free
        // writes), content xor-swizzled within the row's 4 16B-groups.
        #pragma unroll
        for (int it = 0; it < 2; ++it) {
            int slot = it * 256 + tid;       // 0..511
            int r = slot >> 2;               // row 0..127
            int g = (slot & 3) ^ (r & 3);    // swizzled 16B group
            const float* src = x + (size_t)(m0 + r) * KDIM + kk + g * 8;
            float4 a0 = *(const float4*)src;
            float4 a1 = *(const float4*)(src + 4);
            bf16x8 v = {(__bf16)a0.x, (__bf16)a0.y, (__bf16)a0.z, (__bf16)a0.w,
                        (__bf16)a1.x, (__bf16)a1.y, (__bf16)a1.z, (__bf16)a1.w};
            *(bf16x8*)(AsL + slot * 8) = v;
        }
        // B staging: ld chunk 32k x 32n, transposed to [n][k]
        #pragma unroll
        for (int i2 = 0; i2 < 4; ++i2) {
            int j = i2 * 256 + tid;
            int r = j >> 5, n = j & 31;
            BsL[n * 32 + r] = (__bf16)ld[(size_t)(kk + r) * RANK + n];
        }
        __syncthreads();
        bf16x8 av[2], bv[2];
        #pragma unroll
        for (int i = 0; i < 2; ++i) {
            int row  = wave * 32 + i * 16 + mrow;
            int slot = row * 4 + (quad ^ (row & 3));
            av[i] = *(const bf16x8*)(AsL + slot * 8);
        }
        #pragma unroll
        for (int j = 0; j < 2; ++j)
            bv[j] = *(const bf16x8*)(BsL + (j * 16 + mrow) * 32 + quad * 8);
        #pragma unroll
        for (int i = 0; i < 2; ++i)
            #pragma unroll
            for (int j = 0; j < 2; ++j)
                acc[i][j] = __builtin_amdgcn_mfma_f32_16x16x32_bf16(av[i], bv[j], acc[i][j], 0, 0, 0);
        __syncthreads();
    }
    float* tout = tws + (size_t)sp * MDIM * RANK;
    #pragma unroll
    for (int i = 0; i < 2; ++i)
        #pragma unroll
        for (int j = 0; j < 2; ++j)
            #pragma unroll
            for (int r = 0; r < 4; ++r) {
                int rowg = m0 + wave * 32 + i * 16 + quad * 4 + r;
                int col  = j * 16 + mrow;
                tout[(size_t)rowg * RANK + col] = acc[i][j][r];
            }
}

// -------- WPREP: dequant int4 W + transpose -> Wt[n][k] (tail = lora_up) ----
__global__ __launch_bounds__(256) void k_wprep(const int*   __restrict__ qw,
                                               const float* __restrict__ wsc,
                                               const float* __restrict__ lu,
                                               __bf16* __restrict__ Wt) {
    __shared__ __attribute__((aligned(16))) __bf16 tile[64][68];   // +4 pad
    int widx = blockIdx.x;
    int tid  = threadIdx.x;
    int n0 = (widx & 63) * 64;
    int kt = widx >> 6;               // 0..64
    int k0 = kt * 64;
    int tr = tid >> 4;                // 0..15
    int tc = (tid & 15) * 4;          // 0,4,...,60
    if (kt < NG) {
        float4 ws = *(const float4*)(wsc + (size_t)kt * NDIM + n0 + tc);
        #pragma unroll
        for (int r = tr; r < 64; r += 16) {
            int4 q = *(const int4*)(qw + (size_t)(k0 + r) * NDIM + n0 + tc);
            tile[r][tc + 0] = (__bf16)((float)q.x * ws.x);
            tile[r][tc + 1] = (__bf16)((float)q.y * ws.y);
            tile[r][tc + 2] = (__bf16)((float)q.z * ws.z);
            tile[r][tc + 3] = (__bf16)((float)q.w * ws.w);
        }
    } else {
        #pragma unroll
        for (int r = tr; r < 64; r += 16) {
            if (r < RANK) {
                float4 lv = *(const float4*)(lu + (size_t)r * NDIM + n0 + tc);
                tile[r][tc + 0] = (__bf16)lv.x;
                tile[r][tc + 1] = (__bf16)lv.y;
                tile[r][tc + 2] = (__bf16)lv.z;
                tile[r][tc + 3] = (__bf16)lv.w;
            } else {
                tile[r][tc + 0] = (__bf16)0.f;
                tile[r][tc + 1] = (__bf16)0.f;
                tile[r][tc + 2] = (__bf16)0.f;
                tile[r][tc + 3] = (__bf16)0.f;
            }
        }
    }
    __syncthreads();
    int nn = tid >> 3;            // 0..31
    int ks = (tid & 7) * 8;       // 0..56
    #pragma unroll
    for (int p = 0; p < 2; ++p) {
        int n = nn + p * 32;
        bf16x8 v;
        #pragma unroll
        for (int e = 0; e < 8; ++e) v[e] = tile[ks + e][n];
        *(bf16x8*)(Wt + (size_t)(n0 + n) * KE + k0 + ks) = v;
    }
}

// ------- QUANT: smooth + per-group int4 quant/dequant of x -> A rows --------
__global__ __launch_bounds__(256) void k_quant(const float* __restrict__ x,
                                               const float* __restrict__ smooth,
                                               __bf16* __restrict__ A) {
    int row = blockIdx.x;
    int tid = threadIdx.x;
    const float4* xr4 = (const float4*)(x + (size_t)row * KDIM);
    const float4* sm4 = (const float4*)smooth;
    __bf16* ar = A + (size_t)row * KE;
    #pragma unroll
    for (int p = 0; p < 4; ++p) {
        int i4 = p * 256 + tid;          // float4 index 0..1023
        float4 xv = xr4[i4];
        float4 sv = sm4[i4];
        float4 xs = {xv.x * __builtin_amdgcn_rcpf(sv.x),
                     xv.y * __builtin_amdgcn_rcpf(sv.y),
                     xv.z * __builtin_amdgcn_rcpf(sv.z),
                     xv.w * __builtin_amdgcn_rcpf(sv.w)};
        float a = fmaxf(fmaxf(fabsf(xs.x), fabsf(xs.y)),
                        fmaxf(fabsf(xs.z), fabsf(xs.w)));
        #pragma unroll
        for (int off = 1; off < 16; off <<= 1)
            a = fmaxf(a, __shfl_xor(a, off, 64));  // 16-lane group = 64 elems
        float ascale = fmaxf(a * (1.0f / 7.0f), 1e-8f);
        float rin = __builtin_amdgcn_rcpf(ascale);
        float q0 = fminf(fmaxf(rintf(xs.x * rin), -8.f), 7.f);
        float q1 = fminf(fmaxf(rintf(xs.y * rin), -8.f), 7.f);
        float q2 = fminf(fmaxf(rintf(xs.z * rin), -8.f), 7.f);
        float q3 = fminf(fmaxf(rintf(xs.w * rin), -8.f), 7.f);
        bf16x4 av = {(__bf16)(q0 * ascale), (__bf16)(q1 * ascale),
                     (__bf16)(q2 * ascale), (__bf16)(q3 * ascale)};
        *(bf16x4*)(ar + i4 * 4) = av;
    }
}

// ---------------------------------------------------------------------------
// Reduce split-K partials, write t (bf16) + zero pad into A cols [4096, 4160)
// ---------------------------------------------------------------------------
__global__ __launch_bounds__(256) void k_fin(const float* __restrict__ tws,
                                             __bf16* __restrict__ A) {
    int idx = blockIdx.x * 256 + threadIdx.x;
    int m = idx >> 4, cq = idx & 15;
    int c = cq * 4;
    bf16x4 v = {(__bf16)0.f, (__bf16)0.f, (__bf16)0.f, (__bf16)0.f};
    if (c < RANK) {
        f32x4 s = {0.f, 0.f, 0.f, 0.f};
        #pragma unroll
        for (int sp = 0; sp < NSPLIT; ++sp) {
            f32x4 p = *(const f32x4*)(tws + ((size_t)sp * MDIM + m) * RANK + c);
            s.x += p.x; s.y += p.y; s.z += p.z; s.w += p.w;
        }
        v[0] = (__bf16)s.x; v[1] = (__bf16)s.y; v[2] = (__bf16)s.z; v[3] = (__bf16)s.w;
    }
    *(bf16x4*)(A + (size_t)m * KE + KDIM + c) = v;
}

// ---------------------------------------------------------------------------
// Main GEMM — FROZEN at Round-5 best (147 µs): 256x256 tile, BK=64, 8 waves,
// pipelined fragment prefetch with counted lgkmcnt, 2 load-bearing
// barriers/tile, counted vmcnt, setprio, XCD-chunked blockIdx swizzle.
//
// Quadrant order Q00,Q01,Q11,Q10 (fragment reuse, 24 ds_read_b128/tile):
//   P1: consume av0,bv0 [lgkmcnt(4)]  prefetch bv1      stage (t+1,B0)
//   P2: consume bv1     [lgkmcnt(8)]  prefetch av1      stage (t+1,A1)  BAR
//   P3: consume av1     [lgkmcnt(0)]  vmcnt(2) arrival  stage (t+2,A0)  BAR
//   P4: consume (regs only, no wait)  prefetch av0',bv0' stage (t+2,B1)
// vmcnt(2) at P3: oldest 8 of {entry 4 + P1 2 + P2 2 + P3 2} = all of t+1.
// ---------------------------------------------------------------------------
#define NT (KE / 64)          // 65 K-tiles
#define HS 8192               // half-tile elements (128*64)
#define BS 16384              // one buffer's elements (256*64)

#define STAGE(ldsbase, gb, kt, half) do {                                     \
    int _k0 = (kt) * 64;                                                      \
    _Pragma("unroll")                                                         \
    for (int _it = 0; _it < 2; ++_it) {                                       \
        int _c = _it * 512 + tid;                                             \
        int _r = _c >> 3;                                                     \
        int _g = (_c & 7) ^ (_r & 7);                                         \
        __builtin_amdgcn_global_load_lds(                                     \
            GPTR((gb) + (size_t)((half) * 128 + _r) * KE + _k0 + _g * 8),     \
            LPTR((char*)(ldsbase) + (_it * 512 + wave * 64) * 16),            \
            16, 0, 0);                                                        \
    } } while (0)

// issue A-quadrant fragment reads (8 x ds_read_b128) into dst[kstep][i]
#define RD_A(dst, base, qm) do {                                              \
    _Pragma("unroll")                                                         \
    for (int _i = 0; _i < 4; ++_i) {                                          \
        int _row = (qm) * 128 + wm * 64 + _i * 16 + mrow;                     \
        dst[0][_i] = *(const bf16x8*)((const char*)(base) + _row * 128 + ga0 * 16); \
        dst[1][_i] = *(const bf16x8*)((const char*)(base) + _row * 128 + ga1 * 16); \
    } } while (0)

// issue B-quadrant fragment reads (4 x ds_read_b128) into dst[kstep][j]
#define RD_B(dst, base, qn) do {                                              \
    _Pragma("unroll")                                                         \
    for (int _j = 0; _j < 2; ++_j) {                                          \
        int _row = (qn) * 128 + wn * 32 + _j * 16 + mrow;                     \
        dst[0][_j] = *(const bf16x8*)((const char*)(base) + _row * 128 + ga0 * 16); \
        dst[1][_j] = *(const bf16x8*)((const char*)(base) + _row * 128 + ga1 * 16); \
    } } while (0)

// 16 MFMA: one C-quadrant x K=64
#define MMA(qm, qn, AV, BV) do {                                              \
    _Pragma("unroll")                                                         \
    for (int _i = 0; _i < 4; ++_i)                                            \
        _Pragma("unroll")                                                     \
        for (int _j = 0; _j < 2; ++_j) {                                      \
            acc[qm][qn][_i][_j] = __builtin_amdgcn_mfma_f32_16x16x32_bf16(    \
                AV[0][_i], BV[0][_j], acc[qm][qn][_i][_j], 0, 0, 0);          \
            acc[qm][qn][_i][_j] = __builtin_amdgcn_mfma_f32_16x16x32_bf16(    \
                AV[1][_i], BV[1][_j], acc[qm][qn][_i][_j], 0, 0, 0);          \
        } } while (0)

#define SBAR0() __builtin_amdgcn_sched_barrier(0)

__global__ __launch_bounds__(512, 2) void k_gemm(const __bf16* __restrict__ A,
                                                 const __bf16* __restrict__ Wt,
                                                 const float*  __restrict__ bias,
                                                 float* __restrict__ out) {
    __shared__ __attribute__((aligned(16))) __bf16 As[2 * BS];   // 64 KiB
    __shared__ __attribute__((aligned(16))) __bf16 Bs[2 * BS];   // 64 KiB
    int tid  = threadIdx.x;
    int lane = tid & 63;
    int wave = tid >> 6;          // 0..7
    int quad = lane >> 4;
    int mrow = lane & 15;
    int wm = wave >> 2;           // 0..1  (M half of wave grid)
    int wn = wave & 3;            // 0..3  (N quarter of wave grid)

    // XCD-chunked swizzle: linear dispatch id -> (xcd, slot); each XCD gets
    // 32 consecutive work ids = 2 full grid rows (A-panel L2 reuse).
    int lin = blockIdx.y * 16 + blockIdx.x;        // dispatch order (x fastest)
    int swz = (lin & 7) * 32 + (lin >> 3);         // 256 = 8 * 32, bijective
    int m0 = (swz >> 4) * 256, n0 = (swz & 15) * 256;

    const __bf16* Ab = A  + (size_t)m0 * KE;
    const __bf16* Bb = Wt + (size_t)n0 * KE;

    // per-lane swizzled 16B-group index for the two 32-wide k-steps
    int ga0 = quad ^ (mrow & 7);
    int ga1 = (quad + 4) ^ (mrow & 7);

    f32x4 z = {0.f, 0.f, 0.f, 0.f};
    f32x4 acc[2][2][4][2];
    #pragma unroll
    for (int a = 0; a < 2; ++a)
        #pragma unroll
        for (int b = 0; b < 2; ++b)
            #pragma unroll
            for (int i = 0; i < 4; ++i)
                #pragma unroll
                for (int j = 0; j < 2; ++j) acc[a][b][i][j] = z;

    // Prologue: tile0 fully + tile1's (A0,B1), wait tile0, preload fragments.
    STAGE(As,           Ab, 0, 0);   // (0,A0)
    STAGE(Bs + HS,      Bb, 0, 1);   // (0,B1)
    STAGE(Bs,           Bb, 0, 0);   // (0,B0)
    STAGE(As + HS,      Ab, 0, 1);   // (0,A1)
    STAGE(As + BS,      Ab, 1, 0);   // (1,A0)
    STAGE(Bs + BS + HS, Bb, 1, 1);   // (1,B1)
    asm volatile("s_waitcnt vmcnt(4)" ::: "memory");
    __builtin_amdgcn_s_barrier();
    SBAR0();

    bf16x8 av0[2][4], av1[2][4], bv0[2][2], bv1[2][2];
    RD_A(av0, As, 0);                // tile0 Q00 fragments
    RD_B(bv0, Bs, 0);
    SBAR0();

    for (int t = 0; t < NT; ++t) {
        int cur = t & 1;
        const __bf16* Acur = As + cur * BS;
        const __bf16* Bcur = Bs + cur * BS;
        __bf16* Anx = As + (cur ^ 1) * BS;
        __bf16* Bnx = Bs + (cur ^ 1) * BS;
        __bf16* Acu = As + cur * BS;
        __bf16* Bcu = Bs + cur * BS;
        bool s1 = (t + 1 < NT), s2 = (t + 2 < NT);

        // ---- P1 (Q00): consume av0,bv0; prefetch bv1; stage (t+1,B0) ----
        if (s1) STAGE(Bnx, Bb, t + 1, 0);
        RD_B(bv1, Bcur, 1);
        SBAR0();
        asm volatile("s_waitcnt lgkmcnt(4)" ::: "memory");   // av0,bv0 ready
        SBAR0();
        __builtin_amdgcn_s_setprio(1);
        MMA(0, 0, av0, bv0);
        __builtin_amdgcn_s_setprio(0);

        // ---- P2 (Q01): consume bv1; prefetch av1; stage (t+1,A1) ----
        if (s1) STAGE(Anx + HS, Ab, t + 1, 1);
        RD_A(av1, Acur, 1);
        SBAR0();
        asm volatile("s_waitcnt lgkmcnt(8)" ::: "memory");   // bv1 ready
        SBAR0();
        __builtin_amdgcn_s_setprio(1);
        MMA(0, 1, av0, bv1);
        __builtin_amdgcn_s_setprio(0);
        __builtin_amdgcn_s_barrier();    // av0-region free for P3 DMA;
        SBAR0();                         // bv1-region free for P4 DMA

        // ---- P3 (Q11): consume av1; stage (t+2,A0); t+1 arrival wait ----
        if (s2) STAGE(Acu, Ab, t + 2, 0);
        SBAR0();
        asm volatile("s_waitcnt lgkmcnt(0)" ::: "memory");   // av1 ready
        SBAR0();
        __builtin_amdgcn_s_setprio(1);
        MMA(1, 1, av1, bv1);
        __builtin_amdgcn_s_setprio(0);
        if (s2) { asm volatile("s_waitcnt vmcnt(2)" ::: "memory"); }
        else    { asm volatile("s_waitcnt vmcnt(0)" ::: "memory"); }
        __builtin_amdgcn_s_barrier();    // t+1 halves visible to all waves
        SBAR0();

        // ---- P4 (Q10): regs only; stage (t+2,B1); prefetch next av0,bv0 ----
        if (s2) STAGE(Bcu + HS, Bb, t + 2, 1);
        if (s1) RD_A(av0, Anx, 0);       // av0 dead since P2 — safe overwrite
        SBAR0();
        __builtin_amdgcn_s_setprio(1);
        MMA(1, 0, av1, bv0);
        __builtin_amdgcn_s_setprio(0);
        if (s1) RD_B(bv0, Bnx, 0);       // after MFMA issue (WAR via HW)
        SBAR0();
    }

    // epilogue: C/D layout col = lane&15, row = quad*4 + reg (m89/m91)
    #pragma unroll
    for (int qn = 0; qn < 2; ++qn)
        #pragma unroll
        for (int j = 0; j < 2; ++j) {
            int col = n0 + qn * 128 + wn * 32 + j * 16 + mrow;
            float bvs = bias[col];
            #pragma unroll
            for (int qm = 0; qm < 2; ++qm)
                #pragma unroll
                for (int i = 0; i < 4; ++i) {
                    int rbase = m0 + qm * 128 + wm * 64 + i * 16 + quad * 4;
                    #pragma unroll
                    for (int r = 0; r < 4; ++r)
                        __builtin_nontemporal_store(acc[qm][qn][i][j][r] + bvs,
                                                    &out[(size_t)(rbase + r) * NDIM + col]);
                }
        }
}

extern "C" void kernel_launch(void* const* d_in, const int* in_sizes, int n_in,
                              void* d_out, int out_size, void* d_ws, size_t ws_size,
                              hipStream_t stream) {
    const float* x    = (const float*)d_in[0];
    const int*   qw   = (const int*)  d_in[1];
    const float* wsc  = (const float*)d_in[2];
    const float* ld   = (const float*)d_in[3];
    const float* lu   = (const float*)d_in[4];
    const float* sm   = (const float*)d_in[5];
    const float* bias = (const float*)d_in[6];
    float* out = (float*)d_out;

    char* ws = (char*)d_ws;
    __bf16* A   = (__bf16*)ws;                                   // M*KE bf16
    __bf16* Wt  = (__bf16*)(ws + (size_t)MDIM * KE * 2);         // N*KE bf16
    float*  tws = (float*) (ws + (size_t)MDIM * KE * 4);         // NSPLIT*M*RANK f32

    k_lorat<<<32 * NSPLIT, 256, 0, stream>>>(x, ld, tws);
    k_wprep<<<65 * 64, 256, 0, stream>>>(qw, wsc, lu, Wt);
    k_quant<<<MDIM, 256, 0, stream>>>(x, sm, A);
    k_fin<<<(MDIM * 16) / 256, 256, 0, stream>>>(tws, A);
    k_gemm<<<dim3(NDIM / 256, MDIM / 256), 512, 0, stream>>>(A, Wt, bias, out);
}

// Round 7
// 306.544 us; speedup vs baseline: 1.0650x; 1.0650x over previous
//
#include <hip/hip_runtime.h>
#include <hip/hip_bf16.h>
#include <stdint.h>

#define GSIZE 64
#define MDIM 4096
#define KDIM 4096
#define NDIM 4096
#define RANK 32
#define KE   4160   // K + 32 (lora) + 32 (zero pad) -> 65 * 64
#define NG   64     // K / GSIZE
#define NSPLIT 8    // split-K factor for lora-down GEMM

#define N_LORATQ 256                    // 32 m-tiles x 8 splits
#define N_WPREP  (65 * 64)              // 4160
#define NBLOCKS  (N_LORATQ + N_WPREP)   // 4416

typedef __bf16 bf16x4 __attribute__((ext_vector_type(4)));
typedef __bf16 bf16x8 __attribute__((ext_vector_type(8)));
typedef float  f32x4  __attribute__((ext_vector_type(4)));

#define GPTR(p) ((__attribute__((address_space(1))) void*)(uintptr_t)(p))
#define LPTR(p) ((__attribute__((address_space(3))) void*)(p))

// ---------------------------------------------------------------------------
// Fused prep kernel, 512-thread blocks. Round-6 change: QUANT is fused INTO
// LORAT (role LORATQ): each (m0,sp) block reads x[m0:+128, sp*512:+512) ONCE
// — first quantizing it (smooth -> 64-group amax via 16-lane shfl -> A),
// then running the lora-down MFMA pass on the same (now L2-hot) chunk.
// Eliminates one full 67MB x read + the serial k_quant dispatch, and the
// re-fused single kernel restores cross-role overlap (round-6 showed the
// 3-way split LOST 15 µs to serial ramps/tails: occupancy theory falsified).
// LORATQ widened to 8 waves (2/SIMD) to fix LORAT's 1-wave/SIMD latency.
// ---------------------------------------------------------------------------
__global__ __launch_bounds__(512) void k_prep(const float* __restrict__ x,
                                              const int*   __restrict__ qw,
                                              const float* __restrict__ wsc,
                                              const float* __restrict__ ld,
                                              const float* __restrict__ lu,
                                              const float* __restrict__ smooth,
                                              __bf16* __restrict__ A,
                                              __bf16* __restrict__ Wt,
                                              float* __restrict__ tws) {
    __shared__ __attribute__((aligned(16))) char smem[10240];
    int b   = blockIdx.x;
    int tid = threadIdx.x;

    if (b < N_LORATQ) {
        // ---------------- LORATQ role ----------------
        int m0    = (b & 31) * 128;
        int sp    = b >> 5;                     // 0..7
        int kbase = sp * 512;

        // ---- pass 1: quantize this block's x chunk -> A ----
        {
            int c4 = tid & 127;                 // float4 col within 512
            int r0 = tid >> 7;                  // 0..3
            float4 sv = *(const float4*)(smooth + kbase + c4 * 4);
            float4 si = {__builtin_amdgcn_rcpf(sv.x), __builtin_amdgcn_rcpf(sv.y),
                         __builtin_amdgcn_rcpf(sv.z), __builtin_amdgcn_rcpf(sv.w)};
            #pragma unroll 4
            for (int p = 0; p < 32; ++p) {
                int row = r0 + p * 4;           // covers 0..127
                float4 xv = *(const float4*)(x + (size_t)(m0 + row) * KDIM + kbase + c4 * 4);
                float4 xs = {xv.x * si.x, xv.y * si.y, xv.z * si.z, xv.w * si.w};
                float a = fmaxf(fmaxf(fabsf(xs.x), fabsf(xs.y)),
                                fmaxf(fabsf(xs.z), fabsf(xs.w)));
                #pragma unroll
                for (int off = 1; off < 16; off <<= 1)
                    a = fmaxf(a, __shfl_xor(a, off, 64));   // 16-lane grp = 64 elems
                float ascale = fmaxf(a * (1.0f / 7.0f), 1e-8f);
                float rin = __builtin_amdgcn_rcpf(ascale);
                float q0 = fminf(fmaxf(rintf(xs.x * rin), -8.f), 7.f);
                float q1 = fminf(fmaxf(rintf(xs.y * rin), -8.f), 7.f);
                float q2 = fminf(fmaxf(rintf(xs.z * rin), -8.f), 7.f);
                float q3 = fminf(fmaxf(rintf(xs.w * rin), -8.f), 7.f);
                bf16x4 av = {(__bf16)(q0 * ascale), (__bf16)(q1 * ascale),
                             (__bf16)(q2 * ascale), (__bf16)(q3 * ascale)};
                *(bf16x4*)(A + (size_t)(m0 + row) * KE + kbase + c4 * 4) = av;
            }
        }

        // ---- pass 2: lora-down MFMA on the same chunk (L2-hot) ----
        __bf16* AsL = (__bf16*)smem;            // [128][32], xor-swizzled
        __bf16* BsL = (__bf16*)(smem + 8192);   // [32 n][32 k]
        int lane = tid & 63;
        int wave = tid >> 6;                    // 0..7
        int quad = lane >> 4;
        int mrow = lane & 15;

        f32x4 z = {0.f, 0.f, 0.f, 0.f};
        f32x4 acc[2];
        acc[0] = z; acc[1] = z;

        for (int step = 0; step < 16; ++step) {
            int kk = kbase + step * 32;
            // A staging: one slot per thread (512 slots), linear writes,
            // content xor-swizzled within the row's 4 16B-groups.
            {
                int slot = tid;                  // 0..511
                int r = slot >> 2;               // row 0..127
                int g = (slot & 3) ^ (r & 3);    // swizzled 16B group
                const float* src = x + (size_t)(m0 + r) * KDIM + kk + g * 8;
                float4 a0 = *(const float4*)src;
                float4 a1 = *(const float4*)(src + 4);
                bf16x8 v = {(__bf16)a0.x, (__bf16)a0.y, (__bf16)a0.z, (__bf16)a0.w,
                            (__bf16)a1.x, (__bf16)a1.y, (__bf16)a1.z, (__bf16)a1.w};
                *(bf16x8*)(AsL + slot * 8) = v;
            }
            // B staging: ld chunk 32k x 32n, transposed to [n][k]
            #pragma unroll
            for (int i2 = 0; i2 < 2; ++i2) {
                int j = i2 * 512 + tid;
                int r = j >> 5, n = j & 31;
                BsL[n * 32 + r] = (__bf16)ld[(size_t)(kk + r) * RANK + n];
            }
            __syncthreads();
            bf16x8 av, bv[2];
            {
                int row  = wave * 16 + mrow;
                int slot = row * 4 + (quad ^ (row & 3));
                av = *(const bf16x8*)(AsL + slot * 8);
            }
            #pragma unroll
            for (int j = 0; j < 2; ++j)
                bv[j] = *(const bf16x8*)(BsL + (j * 16 + mrow) * 32 + quad * 8);
            #pragma unroll
            for (int j = 0; j < 2; ++j)
                acc[j] = __builtin_amdgcn_mfma_f32_16x16x32_bf16(av, bv[j], acc[j], 0, 0, 0);
            __syncthreads();
        }
        float* tout = tws + (size_t)sp * MDIM * RANK;
        #pragma unroll
        for (int j = 0; j < 2; ++j)
            #pragma unroll
            for (int r = 0; r < 4; ++r) {
                int rowg = m0 + wave * 16 + quad * 4 + r;
                int col  = j * 16 + mrow;
                tout[(size_t)rowg * RANK + col] = acc[j][r];
            }
        return;
    }

    {
        // ---------------- WPREP role: one 64x64 tile (512 threads) ----------
        __bf16 (*tile)[68] = (__bf16(*)[68])smem;   // +4 pad
        int widx = b - N_LORATQ;
        int n0 = (widx & 63) * 64;
        int kt = widx >> 6;               // 0..64
        int k0 = kt * 64;
        int tr = tid >> 4;                // 0..31
        int tc = (tid & 15) * 4;          // 0,4,...,60
        if (kt < NG) {
            float4 ws = *(const float4*)(wsc + (size_t)kt * NDIM + n0 + tc);
            #pragma unroll
            for (int r = tr; r < 64; r += 32) {
                int4 q = *(const int4*)(qw + (size_t)(k0 + r) * NDIM + n0 + tc);
                tile[r][tc + 0] = (__bf16)((float)q.x * ws.x);
                tile[r][tc + 1] = (__bf16)((float)q.y * ws.y);
                tile[r][tc + 2] = (__bf16)((float)q.z * ws.z);
                tile[r][tc + 3] = (__bf16)((float)q.w * ws.w);
            }
        } else {
            #pragma unroll
            for (int r = tr; r < 64; r += 32) {
                if (r < RANK) {
                    float4 lv = *(const float4*)(lu + (size_t)r * NDIM + n0 + tc);
                    tile[r][tc + 0] = (__bf16)lv.x;
                    tile[r][tc + 1] = (__bf16)lv.y;
                    tile[r][tc + 2] = (__bf16)lv.z;
                    tile[r][tc + 3] = (__bf16)lv.w;
                } else {
                    tile[r][tc + 0] = (__bf16)0.f;
                    tile[r][tc + 1] = (__bf16)0.f;
                    tile[r][tc + 2] = (__bf16)0.f;
                    tile[r][tc + 3] = (__bf16)0.f;
                }
            }
        }
        __syncthreads();
        int nn = tid >> 3;            // 0..63
        int ks = (tid & 7) * 8;       // 0..56
        bf16x8 v;
        #pragma unroll
        for (int e = 0; e < 8; ++e) v[e] = tile[ks + e][nn];
        *(bf16x8*)(Wt + (size_t)(n0 + nn) * KE + k0 + ks) = v;
    }
}

// ---------------------------------------------------------------------------
// Reduce split-K partials, write t (bf16) + zero pad into A cols [4096, 4160)
// ---------------------------------------------------------------------------
__global__ __launch_bounds__(256) void k_fin(const float* __restrict__ tws,
                                             __bf16* __restrict__ A) {
    int idx = blockIdx.x * 256 + threadIdx.x;
    int m = idx >> 4, cq = idx & 15;
    int c = cq * 4;
    bf16x4 v = {(__bf16)0.f, (__bf16)0.f, (__bf16)0.f, (__bf16)0.f};
    if (c < RANK) {
        f32x4 s = {0.f, 0.f, 0.f, 0.f};
        #pragma unroll
        for (int sp = 0; sp < NSPLIT; ++sp) {
            f32x4 p = *(const f32x4*)(tws + ((size_t)sp * MDIM + m) * RANK + c);
            s.x += p.x; s.y += p.y; s.z += p.z; s.w += p.w;
        }
        v[0] = (__bf16)s.x; v[1] = (__bf16)s.y; v[2] = (__bf16)s.z; v[3] = (__bf16)s.w;
    }
    *(bf16x4*)(A + (size_t)m * KE + KDIM + c) = v;
}

// ---------------------------------------------------------------------------
// Main GEMM — FROZEN at Round-5 best (146 µs): 256x256 tile, BK=64, 8 waves,
// pipelined fragment prefetch with counted lgkmcnt, 2 load-bearing
// barriers/tile, counted vmcnt, setprio, XCD-chunked blockIdx swizzle.
//
// Quadrant order Q00,Q01,Q11,Q10 (fragment reuse, 24 ds_read_b128/tile):
//   P1: consume av0,bv0 [lgkmcnt(4)]  prefetch bv1      stage (t+1,B0)
//   P2: consume bv1     [lgkmcnt(8)]  prefetch av1      stage (t+1,A1)  BAR
//   P3: consume av1     [lgkmcnt(0)]  vmcnt(2) arrival  stage (t+2,A0)  BAR
//   P4: consume (regs only, no wait)  prefetch av0',bv0' stage (t+2,B1)
// vmcnt(2) at P3: oldest 8 of {entry 4 + P1 2 + P2 2 + P3 2} = all of t+1.
// ---------------------------------------------------------------------------
#define NT (KE / 64)          // 65 K-tiles
#define HS 8192               // half-tile elements (128*64)
#define BS 16384              // one buffer's elements (256*64)

#define STAGE(ldsbase, gb, kt, half) do {                                     \
    int _k0 = (kt) * 64;                                                      \
    _Pragma("unroll")                                                         \
    for (int _it = 0; _it < 2; ++_it) {                                       \
        int _c = _it * 512 + tid;                                             \
        int _r = _c >> 3;                                                     \
        int _g = (_c & 7) ^ (_r & 7);                                         \
        __builtin_amdgcn_global_load_lds(                                     \
            GPTR((gb) + (size_t)((half) * 128 + _r) * KE + _k0 + _g * 8),     \
            LPTR((char*)(ldsbase) + (_it * 512 + wave * 64) * 16),            \
            16, 0, 0);                                                        \
    } } while (0)

// issue A-quadrant fragment reads (8 x ds_read_b128) into dst[kstep][i]
#define RD_A(dst, base, qm) do {                                              \
    _Pragma("unroll")                                                         \
    for (int _i = 0; _i < 4; ++_i) {                                          \
        int _row = (qm) * 128 + wm * 64 + _i * 16 + mrow;                     \
        dst[0][_i] = *(const bf16x8*)((const char*)(base) + _row * 128 + ga0 * 16); \
        dst[1][_i] = *(const bf16x8*)((const char*)(base) + _row * 128 + ga1 * 16); \
    } } while (0)

// issue B-quadrant fragment reads (4 x ds_read_b128) into dst[kstep][j]
#define RD_B(dst, base, qn) do {                                              \
    _Pragma("unroll")                                                         \
    for (int _j = 0; _j < 2; ++_j) {                                          \
        int _row = (qn) * 128 + wn * 32 + _j * 16 + mrow;                     \
        dst[0][_j] = *(const bf16x8*)((const char*)(base) + _row * 128 + ga0 * 16); \
        dst[1][_j] = *(const bf16x8*)((const char*)(base) + _row * 128 + ga1 * 16); \
    } } while (0)

// 16 MFMA: one C-quadrant x K=64
#define MMA(qm, qn, AV, BV) do {                                              \
    _Pragma("unroll")                                                         \
    for (int _i = 0; _i < 4; ++_i)                                            \
        _Pragma("unroll")                                                     \
        for (int _j = 0; _j < 2; ++_j) {                                      \
            acc[qm][qn][_i][_j] = __builtin_amdgcn_mfma_f32_16x16x32_bf16(    \
                AV[0][_i], BV[0][_j], acc[qm][qn][_i][_j], 0, 0, 0);          \
            acc[qm][qn][_i][_j] = __builtin_amdgcn_mfma_f32_16x16x32_bf16(    \
                AV[1][_i], BV[1][_j], acc[qm][qn][_i][_j], 0, 0, 0);          \
        } } while (0)

#define SBAR0() __builtin_amdgcn_sched_barrier(0)

__global__ __launch_bounds__(512, 2) void k_gemm(const __bf16* __restrict__ A,
                                                 const __bf16* __restrict__ Wt,
                                                 const float*  __restrict__ bias,
                                                 float* __restrict__ out) {
    __shared__ __attribute__((aligned(16))) __bf16 As[2 * BS];   // 64 KiB
    __shared__ __attribute__((aligned(16))) __bf16 Bs[2 * BS];   // 64 KiB
    int tid  = threadIdx.x;
    int lane = tid & 63;
    int wave = tid >> 6;          // 0..7
    int quad = lane >> 4;
    int mrow = lane & 15;
    int wm = wave >> 2;           // 0..1  (M half of wave grid)
    int wn = wave & 3;            // 0..3  (N quarter of wave grid)

    // XCD-chunked swizzle: linear dispatch id -> (xcd, slot); each XCD gets
    // 32 consecutive work ids = 2 full grid rows (A-panel L2 reuse).
    int lin = blockIdx.y * 16 + blockIdx.x;        // dispatch order (x fastest)
    int swz = (lin & 7) * 32 + (lin >> 3);         // 256 = 8 * 32, bijective
    int m0 = (swz >> 4) * 256, n0 = (swz & 15) * 256;

    const __bf16* Ab = A  + (size_t)m0 * KE;
    const __bf16* Bb = Wt + (size_t)n0 * KE;

    // per-lane swizzled 16B-group index for the two 32-wide k-steps
    int ga0 = quad ^ (mrow & 7);
    int ga1 = (quad + 4) ^ (mrow & 7);

    f32x4 z = {0.f, 0.f, 0.f, 0.f};
    f32x4 acc[2][2][4][2];
    #pragma unroll
    for (int a = 0; a < 2; ++a)
        #pragma unroll
        for (int b = 0; b < 2; ++b)
            #pragma unroll
            for (int i = 0; i < 4; ++i)
                #pragma unroll
                for (int j = 0; j < 2; ++j) acc[a][b][i][j] = z;

    // Prologue: tile0 fully + tile1's (A0,B1), wait tile0, preload fragments.
    STAGE(As,           Ab, 0, 0);   // (0,A0)
    STAGE(Bs + HS,      Bb, 0, 1);   // (0,B1)
    STAGE(Bs,           Bb, 0, 0);   // (0,B0)
    STAGE(As + HS,      Ab, 0, 1);   // (0,A1)
    STAGE(As + BS,      Ab, 1, 0);   // (1,A0)
    STAGE(Bs + BS + HS, Bb, 1, 1);   // (1,B1)
    asm volatile("s_waitcnt vmcnt(4)" ::: "memory");
    __builtin_amdgcn_s_barrier();
    SBAR0();

    bf16x8 av0[2][4], av1[2][4], bv0[2][2], bv1[2][2];
    RD_A(av0, As, 0);                // tile0 Q00 fragments
    RD_B(bv0, Bs, 0);
    SBAR0();

    for (int t = 0; t < NT; ++t) {
        int cur = t & 1;
        const __bf16* Acur = As + cur * BS;
        const __bf16* Bcur = Bs + cur * BS;
        __bf16* Anx = As + (cur ^ 1) * BS;
        __bf16* Bnx = Bs + (cur ^ 1) * BS;
        __bf16* Acu = As + cur * BS;
        __bf16* Bcu = Bs + cur * BS;
        bool s1 = (t + 1 < NT), s2 = (t + 2 < NT);

        // ---- P1 (Q00): consume av0,bv0; prefetch bv1; stage (t+1,B0) ----
        if (s1) STAGE(Bnx, Bb, t + 1, 0);
        RD_B(bv1, Bcur, 1);
        SBAR0();
        asm volatile("s_waitcnt lgkmcnt(4)" ::: "memory");   // av0,bv0 ready
        SBAR0();
        __builtin_amdgcn_s_setprio(1);
        MMA(0, 0, av0, bv0);
        __builtin_amdgcn_s_setprio(0);

        // ---- P2 (Q01): consume bv1; prefetch av1; stage (t+1,A1) ----
        if (s1) STAGE(Anx + HS, Ab, t + 1, 1);
        RD_A(av1, Acur, 1);
        SBAR0();
        asm volatile("s_waitcnt lgkmcnt(8)" ::: "memory");   // bv1 ready
        SBAR0();
        __builtin_amdgcn_s_setprio(1);
        MMA(0, 1, av0, bv1);
        __builtin_amdgcn_s_setprio(0);
        __builtin_amdgcn_s_barrier();    // av0-region free for P3 DMA;
        SBAR0();                         // bv1-region free for P4 DMA

        // ---- P3 (Q11): consume av1; stage (t+2,A0); t+1 arrival wait ----
        if (s2) STAGE(Acu, Ab, t + 2, 0);
        SBAR0();
        asm volatile("s_waitcnt lgkmcnt(0)" ::: "memory");   // av1 ready
        SBAR0();
        __builtin_amdgcn_s_setprio(1);
        MMA(1, 1, av1, bv1);
        __builtin_amdgcn_s_setprio(0);
        if (s2) { asm volatile("s_waitcnt vmcnt(2)" ::: "memory"); }
        else    { asm volatile("s_waitcnt vmcnt(0)" ::: "memory"); }
        __builtin_amdgcn_s_barrier();    // t+1 halves visible to all waves
        SBAR0();

        // ---- P4 (Q10): regs only; stage (t+2,B1); prefetch next av0,bv0 ----
        if (s2) STAGE(Bcu + HS, Bb, t + 2, 1);
        if (s1) RD_A(av0, Anx, 0);       // av0 dead since P2 — safe overwrite
        SBAR0();
        __builtin_amdgcn_s_setprio(1);
        MMA(1, 0, av1, bv0);
        __builtin_amdgcn_s_setprio(0);
        if (s1) RD_B(bv0, Bnx, 0);       // after MFMA issue (WAR via HW)
        SBAR0();
    }

    // epilogue: C/D layout col = lane&15, row = quad*4 + reg (m89/m91)
    #pragma unroll
    for (int qn = 0; qn < 2; ++qn)
        #pragma unroll
        for (int j = 0; j < 2; ++j) {
            int col = n0 + qn * 128 + wn * 32 + j * 16 + mrow;
            float bvs = bias[col];
            #pragma unroll
            for (int qm = 0; qm < 2; ++qm)
                #pragma unroll
                for (int i = 0; i < 4; ++i) {
                    int rbase = m0 + qm * 128 + wm * 64 + i * 16 + quad * 4;
                    #pragma unroll
                    for (int r = 0; r < 4; ++r)
                        __builtin_nontemporal_store(acc[qm][qn][i][j][r] + bvs,
                                                    &out[(size_t)(rbase + r) * NDIM + col]);
                }
        }
}

extern "C" void kernel_launch(void* const* d_in, const int* in_sizes, int n_in,
                              void* d_out, int out_size, void* d_ws, size_t ws_size,
                              hipStream_t stream) {
    const float* x    = (const float*)d_in[0];
    const int*   qw   = (const int*)  d_in[1];
    const float* wsc  = (const float*)d_in[2];
    const float* ld   = (const float*)d_in[3];
    const float* lu   = (const float*)d_in[4];
    const float* sm   = (const float*)d_in[5];
    const float* bias = (const float*)d_in[6];
    float* out = (float*)d_out;

    char* ws = (char*)d_ws;
    __bf16* A   = (__bf16*)ws;                                   // M*KE bf16
    __bf16* Wt  = (__bf16*)(ws + (size_t)MDIM * KE * 2);         // N*KE bf16
    float*  tws = (float*) (ws + (size_t)MDIM * KE * 4);         // NSPLIT*M*RANK f32

    k_prep<<<NBLOCKS, 512, 0, stream>>>(x, qw, wsc, ld, lu, sm, A, Wt, tws);
    k_fin<<<(MDIM * 16) / 256, 256, 0, stream>>>(tws, A);
    k_gemm<<<dim3(NDIM / 256, MDIM / 256), 512, 0, stream>>>(A, Wt, bias, out);
}